// Round 3
// baseline (1240.812 us; speedup 1.0000x reference)
//
#include <hip/hip_runtime.h>

#define N_NODES 100000
#define N_EDGES 1600000
#define F_IN    128
#define HC      128     // H * C
#define NGRAPH  64
#define NEG_SLOPE 0.2f

static constexpr int SCAN_NB = (N_NODES + 255) / 256;   // 391
static constexpr int TOT_E   = N_EDGES + N_NODES;       // with self loops

typedef __bf16 bf16x8 __attribute__((ext_vector_type(8)));
typedef float  f32x4  __attribute__((ext_vector_type(4)));

// ---------------- CSR build ----------------

__global__ __launch_bounds__(256) void hist_kernel(const int* __restrict__ ei, int* __restrict__ deg) {
    int i = blockIdx.x * 256 + threadIdx.x;
    if (i < N_EDGES) {
        atomicAdd(&deg[ei[N_EDGES + i]], 1);      // dst of real edge
    } else if (i < TOT_E) {
        atomicAdd(&deg[i - N_EDGES], 1);          // self loop
    }
}

__global__ __launch_bounds__(256) void scan_partial(const int* __restrict__ deg, int* __restrict__ bsum) {
    int i = blockIdx.x * 256 + threadIdx.x;
    int d = (i < N_NODES) ? deg[i] : 0;
    for (int off = 32; off; off >>= 1) d += __shfl_down(d, off);
    __shared__ int wsum[4];
    int lane = threadIdx.x & 63, w = threadIdx.x >> 6;
    if (lane == 0) wsum[w] = d;
    __syncthreads();
    if (threadIdx.x == 0) bsum[blockIdx.x] = wsum[0] + wsum[1] + wsum[2] + wsum[3];
}

__global__ void scan_bsum(const int* __restrict__ bsum, int* __restrict__ boff) {
    __shared__ int sd[512];
    int t = threadIdx.x;
    int v = (t < SCAN_NB) ? bsum[t] : 0;
    sd[t] = v; __syncthreads();
    for (int off = 1; off < 512; off <<= 1) {
        int x = (t >= off) ? sd[t - off] : 0;
        __syncthreads();
        sd[t] += x;
        __syncthreads();
    }
    if (t < SCAN_NB) boff[t] = sd[t] - v;   // exclusive
}

__global__ __launch_bounds__(256) void scan_final(const int* __restrict__ deg, const int* __restrict__ boff,
                                                  int* __restrict__ offs, int* __restrict__ cursor) {
    __shared__ int sd[256];
    int t = threadIdx.x;
    int i = blockIdx.x * 256 + t;
    int d = (i < N_NODES) ? deg[i] : 0;
    sd[t] = d; __syncthreads();
    for (int off = 1; off < 256; off <<= 1) {
        int x = (t >= off) ? sd[t - off] : 0;
        __syncthreads();
        sd[t] += x;
        __syncthreads();
    }
    int incl = sd[t];
    int base = boff[blockIdx.x];
    if (i < N_NODES) {
        offs[i + 1] = base + incl;
        cursor[i]   = base + incl - d;
    }
    if (i == 0) offs[0] = 0;
}

__global__ __launch_bounds__(256) void scatter_kernel(const int* __restrict__ ei, int* __restrict__ cursor,
                                                      int* __restrict__ csr_src) {
    int i = blockIdx.x * 256 + threadIdx.x;
    int s, d;
    if (i < N_EDGES)      { s = ei[i]; d = ei[N_EDGES + i]; }
    else if (i < TOT_E)   { s = i - N_EDGES; d = s; }
    else return;
    int pos = atomicAdd(&cursor[d], 1);
    csr_src[pos] = s;
}

__global__ __launch_bounds__(256) void counts_kernel(const int* __restrict__ batch, int* __restrict__ counts) {
    __shared__ int loc[NGRAPH];
    int t = threadIdx.x;
    if (t < NGRAPH) loc[t] = 0;
    __syncthreads();
    int i = blockIdx.x * 256 + t;
    if (i < N_NODES) atomicAdd(&loc[batch[i]], 1);
    __syncthreads();
    if (t < NGRAPH && loc[t]) atomicAdd(&counts[t], loc[t]);
}

// ---------------- W -> bf16, fragment-ready layout Wt[k>>3][col][k&7] ----------------

__device__ __forceinline__ unsigned short f2bf_rne(float f) {
    unsigned u = __float_as_uint(f);
    u += 0x7fffu + ((u >> 16) & 1u);
    return (unsigned short)(u >> 16);
}

__global__ __launch_bounds__(256) void wtconv_kernel(const float* __restrict__ W, unsigned short* __restrict__ Wt) {
    int i = blockIdx.x * 256 + threadIdx.x;
    if (i >= F_IN * HC) return;
    int k = i >> 7, col = i & 127;
    Wt[(size_t)(k >> 3) * (HC * 8) + col * 8 + (k & 7)] = f2bf_rne(W[i]);
}

// ---------------- GEMM: H = X @ W via MFMA bf16 ----------------
// block = 256 (4 waves), tile = 64 rows x 128 cols. Wave (wr,wc) owns rows 32*wr..+31,
// cols 64*wc..+63. B-frags in registers (loaded from Wt once). A staged fp32->bf16 in
// LDS with XOR swizzle (kb ^= row&7) so frag ds_read_b128 is ~conflict-free.

__global__ __launch_bounds__(256) void gemm_mfma(const float* __restrict__ X,
                                                 const unsigned short* __restrict__ Wt,
                                                 float* __restrict__ Hout) {
    __shared__ unsigned short A_lds[64 * F_IN];     // 16 KB
    int t = threadIdx.x;
    int lane = t & 63, wave = t >> 6;
    int wc = wave & 1, wr = wave >> 1;
    int base = blockIdx.x * 64;

    // B fragments: Bf[ct][ks], lane holds B[k = 32*ks + 8*(lane>>4) + j][col = 64*wc + 16*ct + (lane&15)]
    bf16x8 Bf[4][4];
    {
        int colb = wc * 64 + (lane & 15);
        int kbb  = lane >> 4;
#pragma unroll
        for (int ct = 0; ct < 4; ++ct)
#pragma unroll
            for (int ks = 0; ks < 4; ++ks) {
                int kb = kbb + 4 * ks;
                Bf[ct][ks] = *(const bf16x8*)&Wt[(size_t)kb * (HC * 8) + (colb + ct * 16) * 8];
            }
    }

    // stage A (64 x 128) fp32 -> bf16, swizzled: byte = row*256 + ((kb ^ (row&7))<<4) + (k&7)*2
#pragma unroll
    for (int it = 0; it < 8; ++it) {
        int i = t + it * 256;
        int row = i >> 5, c4 = i & 31, k0 = c4 * 4;
        float4 v = make_float4(0.f, 0.f, 0.f, 0.f);
        if (base + row < N_NODES) v = ((const float4*)X)[(size_t)(base + row) * 32 + c4];
        unsigned p0 = (unsigned)f2bf_rne(v.x) | ((unsigned)f2bf_rne(v.y) << 16);
        unsigned p1 = (unsigned)f2bf_rne(v.z) | ((unsigned)f2bf_rne(v.w) << 16);
        int byte = row * 256 + (((k0 >> 3) ^ (row & 7)) << 4) + (k0 & 4) * 2;
        uint2 pk; pk.x = p0; pk.y = p1;
        *(uint2*)((char*)A_lds + byte) = pk;
    }
    __syncthreads();

    f32x4 acc[2][4] = {};
#pragma unroll
    for (int ks = 0; ks < 4; ++ks) {
        bf16x8 Af[2];
#pragma unroll
        for (int r = 0; r < 2; ++r) {
            int row = wr * 32 + r * 16 + (lane & 15);
            int kb  = ks * 4 + (lane >> 4);
            int byte = row * 256 + ((kb ^ (row & 7)) << 4);
            Af[r] = *(const bf16x8*)((const char*)A_lds + byte);
        }
#pragma unroll
        for (int ct = 0; ct < 4; ++ct) {
            acc[0][ct] = __builtin_amdgcn_mfma_f32_16x16x32_bf16(Af[0], Bf[ct][ks], acc[0][ct], 0, 0, 0);
            acc[1][ct] = __builtin_amdgcn_mfma_f32_16x16x32_bf16(Af[1], Bf[ct][ks], acc[1][ct], 0, 0, 0);
        }
    }

    // D layout: col = lane&15, row_in_16 = (lane>>4)*4 + reg
#pragma unroll
    for (int r = 0; r < 2; ++r) {
        int row0 = base + wr * 32 + r * 16 + (lane >> 4) * 4;
#pragma unroll
        for (int reg = 0; reg < 4; ++reg) {
            int row = row0 + reg;
            if (row < N_NODES) {
#pragma unroll
                for (int ct = 0; ct < 4; ++ct) {
                    int col = wc * 64 + ct * 16 + (lane & 15);
                    Hout[(size_t)row * HC + col] = acc[r][ct][reg];
                }
            }
        }
    }
}

// ---------------- per-node attention logits ----------------

__global__ __launch_bounds__(256) void alpha_kernel(const float* __restrict__ H,
                                                    const float* __restrict__ a_src, const float* __restrict__ a_dst,
                                                    float* __restrict__ asrc, float* __restrict__ adst) {
    int wid  = (blockIdx.x * 256 + threadIdx.x) >> 6;
    int lane = threadIdx.x & 63;
    if (wid >= N_NODES) return;
    float2 hv = *(const float2*)&H[(size_t)wid * HC + lane * 2];
    int ch = lane * 2;
    float2 as = *(const float2*)&a_src[ch];
    float2 ad = *(const float2*)&a_dst[ch];
    float ps = hv.x * as.x + hv.y * as.y;
    float pd = hv.x * ad.x + hv.y * ad.y;
    for (int off = 16; off; off >>= 1) {
        ps += __shfl_xor(ps, off);
        pd += __shfl_xor(pd, off);
    }
    int head = lane >> 5;
    if ((lane & 31) == 0) {
        asrc[wid * 2 + head] = ps;
        adst[wid * 2 + head] = pd;
    }
}

// ---------------- aggregation (edge weights computed inline) ----------------
// one wave per dst node; half-waves process alternating CSR edges, 4x unrolled.
// mode 0: relu -> Hout row.  mode 1: scaled atomicAdd into pooled[batch[wid]].

__global__ __launch_bounds__(256) void agg_kernel(const int* __restrict__ offs, const int* __restrict__ csr_src,
                                                  const float* __restrict__ asrc, const float* __restrict__ adst,
                                                  const float* __restrict__ Hin, const float* __restrict__ bias,
                                                  float* __restrict__ Hout, int mode,
                                                  const int* __restrict__ batch, const int* __restrict__ counts,
                                                  float* __restrict__ pooled) {
    int wid  = (blockIdx.x * 256 + threadIdx.x) >> 6;
    int lane = threadIdx.x & 63;
    if (wid >= N_NODES) return;
    int beg = offs[wid], end = offs[wid + 1];
    int half = lane >> 5;
    int hl   = lane & 31;          // channels 4*hl .. 4*hl+3
    int head = hl >> 4;
    float2 adv = *(const float2*)&adst[(size_t)wid * 2];
    float madst = head ? adv.y : adv.x;

    float den = 0.f;
    float4 acc = make_float4(0.f, 0.f, 0.f, 0.f);
    const float2* av = (const float2*)asrc;

    int e = beg + half;
    for (; e + 6 < end; e += 8) {
        int s0 = csr_src[e];
        int s1 = csr_src[e + 2];
        int s2 = csr_src[e + 4];
        int s3 = csr_src[e + 6];
        float2 a0 = av[s0], a1 = av[s1], a2 = av[s2], a3 = av[s3];
        float4 h0 = *(const float4*)&Hin[(size_t)s0 * HC + hl * 4];
        float4 h1 = *(const float4*)&Hin[(size_t)s1 * HC + hl * 4];
        float4 h2 = *(const float4*)&Hin[(size_t)s2 * HC + hl * 4];
        float4 h3 = *(const float4*)&Hin[(size_t)s3 * HC + hl * 4];
        float e0 = (head ? a0.y : a0.x) + madst; e0 = e0 > 0.f ? e0 : NEG_SLOPE * e0;
        float e1 = (head ? a1.y : a1.x) + madst; e1 = e1 > 0.f ? e1 : NEG_SLOPE * e1;
        float e2 = (head ? a2.y : a2.x) + madst; e2 = e2 > 0.f ? e2 : NEG_SLOPE * e2;
        float e3 = (head ? a3.y : a3.x) + madst; e3 = e3 > 0.f ? e3 : NEG_SLOPE * e3;
        float w0 = __expf(e0), w1 = __expf(e1), w2 = __expf(e2), w3 = __expf(e3);
        den += (w0 + w1) + (w2 + w3);
        acc.x = fmaf(w3, h3.x, fmaf(w2, h2.x, fmaf(w1, h1.x, fmaf(w0, h0.x, acc.x))));
        acc.y = fmaf(w3, h3.y, fmaf(w2, h2.y, fmaf(w1, h1.y, fmaf(w0, h0.y, acc.y))));
        acc.z = fmaf(w3, h3.z, fmaf(w2, h2.z, fmaf(w1, h1.z, fmaf(w0, h0.z, acc.z))));
        acc.w = fmaf(w3, h3.w, fmaf(w2, h2.w, fmaf(w1, h1.w, fmaf(w0, h0.w, acc.w))));
    }
    for (; e < end; e += 2) {
        int s = csr_src[e];
        float2 a = av[s];
        float el = (head ? a.y : a.x) + madst; el = el > 0.f ? el : NEG_SLOPE * el;
        float w = __expf(el);
        float4 h = *(const float4*)&Hin[(size_t)s * HC + hl * 4];
        den += w;
        acc.x = fmaf(w, h.x, acc.x);
        acc.y = fmaf(w, h.y, acc.y);
        acc.z = fmaf(w, h.z, acc.z);
        acc.w = fmaf(w, h.w, acc.w);
    }

    den   += __shfl_xor(den, 32);
    acc.x += __shfl_xor(acc.x, 32);
    acc.y += __shfl_xor(acc.y, 32);
    acc.z += __shfl_xor(acc.z, 32);
    acc.w += __shfl_xor(acc.w, 32);

    if (half == 0) {
        float inv = 1.0f / den;
        float4 b = *(const float4*)&bias[hl * 4];
        float4 o;
        o.x = fmaf(acc.x, inv, b.x);
        o.y = fmaf(acc.y, inv, b.y);
        o.z = fmaf(acc.z, inv, b.z);
        o.w = fmaf(acc.w, inv, b.w);
        if (mode == 0) {
            o.x = fmaxf(o.x, 0.f); o.y = fmaxf(o.y, 0.f);
            o.z = fmaxf(o.z, 0.f); o.w = fmaxf(o.w, 0.f);
            *(float4*)&Hout[(size_t)wid * HC + hl * 4] = o;
        } else {
            int g = batch[wid];
            float ic = 1.0f / fmaxf((float)counts[g], 1.0f);
            atomicAdd(&pooled[g * HC + hl * 4 + 0], o.x * ic);
            atomicAdd(&pooled[g * HC + hl * 4 + 1], o.y * ic);
            atomicAdd(&pooled[g * HC + hl * 4 + 2], o.z * ic);
            atomicAdd(&pooled[g * HC + hl * 4 + 3], o.w * ic);
        }
    }
}

// ---------------- launch ----------------

extern "C" void kernel_launch(void* const* d_in, const int* in_sizes, int n_in,
                              void* d_out, int out_size, void* d_ws, size_t ws_size,
                              hipStream_t stream) {
    const float* x     = (const float*)d_in[0];
    const int*   ei    = (const int*)d_in[1];
    const int*   batch = (const int*)d_in[2];
    const float* W1    = (const float*)d_in[3];
    const float* a1s   = (const float*)d_in[4];
    const float* a1d   = (const float*)d_in[5];
    const float* b1    = (const float*)d_in[6];
    const float* W2    = (const float*)d_in[7];
    const float* a2s   = (const float*)d_in[8];
    const float* a2d   = (const float*)d_in[9];
    const float* b2    = (const float*)d_in[10];
    float* out = (float*)d_out;

    char* ws = (char*)d_ws;
    const size_t SZ_H = (size_t)N_NODES * HC * sizeof(float);   // 51.2 MB
    float* hA   = (float*)(ws);
    float* hB   = (float*)(ws + SZ_H);
    float* asrc = (float*)(ws + 2 * SZ_H);
    float* adst = asrc + (size_t)N_NODES * 2;
    unsigned short* wt1 = (unsigned short*)(adst + (size_t)N_NODES * 2);
    unsigned short* wt2 = wt1 + F_IN * HC;
    int*   deg  = (int*)(wt2 + F_IN * HC);
    int*   offs = deg + (N_NODES + 1);
    int*   cursor = offs + (N_NODES + 1);
    int*   csr  = cursor + N_NODES;
    int*   bsum = csr + TOT_E;
    int*   boff = bsum + SCAN_NB;
    int*   counts = boff + SCAN_NB;

    hipMemsetAsync(deg, 0, (N_NODES + 1) * sizeof(int), stream);
    hipMemsetAsync(counts, 0, NGRAPH * sizeof(int), stream);
    hipMemsetAsync(out, 0, (size_t)out_size * sizeof(float), stream);

    int histBlocks = (TOT_E + 255) / 256;
    wtconv_kernel<<<(F_IN * HC + 255) / 256, 256, 0, stream>>>(W1, wt1);
    wtconv_kernel<<<(F_IN * HC + 255) / 256, 256, 0, stream>>>(W2, wt2);
    hist_kernel<<<histBlocks, 256, 0, stream>>>(ei, deg);
    counts_kernel<<<(N_NODES + 255) / 256, 256, 0, stream>>>(batch, counts);
    scan_partial<<<SCAN_NB, 256, 0, stream>>>(deg, bsum);
    scan_bsum<<<1, 512, 0, stream>>>(bsum, boff);
    scan_final<<<SCAN_NB, 256, 0, stream>>>(deg, boff, offs, cursor);
    scatter_kernel<<<histBlocks, 256, 0, stream>>>(ei, cursor, csr);

    int gemmBlocks = (N_NODES + 63) / 64;
    int waveBlocks = (N_NODES + 3) / 4;

    // layer 1
    gemm_mfma<<<gemmBlocks, 256, 0, stream>>>(x, wt1, hA);
    alpha_kernel<<<waveBlocks, 256, 0, stream>>>(hA, a1s, a1d, asrc, adst);
    agg_kernel<<<waveBlocks, 256, 0, stream>>>(offs, csr, asrc, adst, hA, b1, hB, 0,
                                               batch, counts, out);

    // layer 2 (pool fused into agg epilogue)
    gemm_mfma<<<gemmBlocks, 256, 0, stream>>>(hB, wt2, hA);
    alpha_kernel<<<waveBlocks, 256, 0, stream>>>(hA, a2s, a2d, asrc, adst);
    agg_kernel<<<waveBlocks, 256, 0, stream>>>(offs, csr, asrc, adst, hA, b2, nullptr, 1,
                                               batch, counts, out);
}